// Round 7
// baseline (118.047 us; speedup 1.0000x reference)
//
#include <hip/hip_runtime.h>
#include <math.h>

// Problem constants (fixed by the reference file)
#define NPOINTS   8192
#define NDIM      64
#define TILE      128          // pairwise output tile per block
#define NT2       64           // NPOINTS / TILE
#define NBLK      2080         // NT2*(NT2+1)/2 triangle tiles
#define NPAIRB    2080         // pair-role blocks (1:1 interleave)
#define NPW       (NPAIRB * 4) // pair waves = 8320
#define GRID      (NBLK + NPAIRB)

// ws dword/float layout:
//  [0, 262144)        W16   : W as bf16, packed 2/dword (8192 rows x 32 dwords)
//  [262144, 393216)   W8    : W as fp8 e4m3, packed 4/dword (8192 rows x 16 dwords)
//  [393216, 401408)   sq    : row squared norms (fp32 exact)
//  [401408, 403488)   partA : per-tile partials of sum 1/(1+d2) over a<b  (2080)
//  [403488, 405568)   a1p   : per-pair-block partials of sum pij*log(pij*(64+d2))
//  [405568, 407648)   a3p   : per-pair-block partials of sum pij
#define WS_W16   0
#define WS_W8    262144
#define WS_SQ    393216
#define WS_PARTA 401408
#define WS_A1P   403488
#define WS_A3P   405568

typedef __attribute__((ext_vector_type(8))) short bf16x8;   // 8 bf16 = 4 VGPRs (MFMA A/B frag)
typedef __attribute__((ext_vector_type(4))) float f32x4;    // MFMA C/D frag
typedef __attribute__((ext_vector_type(2))) float f32x2;

__device__ inline unsigned short f2bf(float f) {            // fp32 -> bf16 RNE
    unsigned u = __float_as_uint(f);
    u += 0x7FFFu + ((u >> 16) & 1u);
    return (unsigned short)(u >> 16);
}
template <bool HI>
__device__ inline f32x2 cvt2(unsigned dw) {                 // 2 fp8 e4m3 -> 2 fp32 (HW cvt)
    return __builtin_amdgcn_cvt_pk_f32_fp8((int)dw, HI);    // word-sel must be constexpr
}

// One wave per row: exact fp32 row norm + bf16 W16; first 64 threads of each
// block also pack the block's 4 rows into fp8 W8 (4 elems/dword, coalesced).
__global__ __launch_bounds__(256) void prep_kernel(const float* __restrict__ W,
                                                   float* __restrict__ sq,
                                                   unsigned* __restrict__ W16,
                                                   unsigned* __restrict__ W8) {
    int t    = threadIdx.x;
    int wid  = (blockIdx.x * 256 + t) >> 6;             // row
    int lane = t & 63;
    float v = W[wid * NDIM + lane];
    float s = v * v;
    #pragma unroll
    for (int m = 32; m >= 1; m >>= 1) s += __shfl_xor(s, m, 64);
    if (lane == 0) sq[wid] = s;
    unsigned bf   = f2bf(v);
    unsigned peer = (unsigned)__shfl_xor((int)bf, 1, 64);
    if ((lane & 1) == 0)                                 // even lane packs (elem l | elem l+1)
        W16[wid * 32 + (lane >> 1)] = (bf & 0xFFFFu) | (peer << 16);
    if (t < 64) {                                        // fp8 pack: 4 rows = 64 dwords/block
        float4 x = *(const float4*)(W + blockIdx.x * 256 + t * 4);
        int lo = __builtin_amdgcn_cvt_pk_fp8_f32(x.x, x.y, 0, false);
        int dw = __builtin_amdgcn_cvt_pk_fp8_f32(x.z, x.w, lo, true);
        W8[blockIdx.x * 64 + t] = (unsigned)dw;
    }
}

// Fused main kernel, roles interleaved 1:1 so both kinds are co-resident:
//   zb even -> MFMA triangle tile z = zb/2 ; zb odd -> pair block pb = zb/2.
// MFMA frag layouts (HW-verified): A/B = X[idx=lane&15][k=(lane>>4)*8+j];
// C/D row=(lane>>4)*4+reg, col=lane&15.
__global__ __launch_bounds__(256) void fused_kernel(const unsigned* __restrict__ W16,
                                                    const unsigned* __restrict__ W8,
                                                    const float* __restrict__ sq,
                                                    const float* __restrict__ pij,
                                                    const int* __restrict__ ii,
                                                    const int* __restrict__ jj,
                                                    int nb,
                                                    float* __restrict__ partA,
                                                    float* __restrict__ a1p,
                                                    float* __restrict__ a3p) {
    __shared__ float red[8];
    int zb = blockIdx.x;
    int t = threadIdx.x, w = t >> 6, lane = t & 63;

    if ((zb & 1) == 0) {
        // ---------------- pairwise MFMA path (bf16, unchanged) ----------------
        int z = zb >> 1;                 // triangle tile id in [0, 2080)
        int by = (int)((129.0 - sqrt(16641.0 - 8.0 * (double)z)) * 0.5);
        while (by * NT2 - by * (by - 1) / 2 > z) --by;
        while ((by + 1) * NT2 - (by + 1) * by / 2 <= z) ++by;
        int bx = by + (z - (by * NT2 - by * (by - 1) / 2));

        int wm = w >> 1, wn = w & 1, quad = lane >> 4, l15 = lane & 15;
        int a0 = by * TILE, b0 = bx * TILE;

        float4 base1[4];                 // 1 + sq[arow + tm*16 + 0..3]
        float  sqb[4];
        {
            int arow = a0 + wm * 64 + quad * 4;
            #pragma unroll
            for (int tm = 0; tm < 4; ++tm) {
                float4 v = *(const float4*)(sq + arow + tm * 16);
                base1[tm] = (float4){1.0f + v.x, 1.0f + v.y, 1.0f + v.z, 1.0f + v.w};
            }
            int bcol = b0 + wn * 64 + l15;
            #pragma unroll
            for (int tn = 0; tn < 4; ++tn) sqb[tn] = sq[bcol + tn * 16];
        }

        f32x4 acc[4][4];
        #pragma unroll
        for (int i = 0; i < 4; ++i)
            #pragma unroll
            for (int j = 0; j < 4; ++j) acc[i][j] = (f32x4){0.f, 0.f, 0.f, 0.f};

        const unsigned* Arow = W16 + (a0 + wm * 64 + l15) * 32;   // row pitch 32 dwords
        const unsigned* Brow = W16 + (b0 + wn * 64 + l15) * 32;
        #pragma unroll
        for (int h = 0; h < 2; ++h) {    // two K=32 halves; frag = 4 dwords, 16B-aligned
            bf16x8 af[4], bfr[4];
            #pragma unroll
            for (int tm = 0; tm < 4; ++tm)
                af[tm] = *(const bf16x8*)(Arow + tm * 16 * 32 + h * 16 + quad * 4);
            #pragma unroll
            for (int tn = 0; tn < 4; ++tn)
                bfr[tn] = *(const bf16x8*)(Brow + tn * 16 * 32 + h * 16 + quad * 4);
            #pragma unroll
            for (int tm = 0; tm < 4; ++tm)
                #pragma unroll
                for (int tn = 0; tn < 4; ++tn)
                    acc[tm][tn] = __builtin_amdgcn_mfma_f32_16x16x32_bf16(af[tm], bfr[tn],
                                                                          acc[tm][tn], 0, 0, 0);
        }

        float ssum = 0.f;
        if (bx > by) {
            #pragma unroll
            for (int tn = 0; tn < 4; ++tn) {
                float c0 = sqb[tn];
                #pragma unroll
                for (int tm = 0; tm < 4; ++tm) {
                    ssum += __builtin_amdgcn_rcpf(fmaf(acc[tm][tn][0], -2.0f, base1[tm].x + c0));
                    ssum += __builtin_amdgcn_rcpf(fmaf(acc[tm][tn][1], -2.0f, base1[tm].y + c0));
                    ssum += __builtin_amdgcn_rcpf(fmaf(acc[tm][tn][2], -2.0f, base1[tm].z + c0));
                    ssum += __builtin_amdgcn_rcpf(fmaf(acc[tm][tn][3], -2.0f, base1[tm].w + c0));
                }
            }
        } else {                         // diagonal tile: strictly-upper only
            int quad4 = quad * 4;
            #pragma unroll
            for (int tn = 0; tn < 4; ++tn) {
                int cl = wn * 64 + tn * 16 + l15;
                float c0 = sqb[tn];
                float b4[4];
                #pragma unroll
                for (int tm = 0; tm < 4; ++tm) {
                    b4[0] = base1[tm].x; b4[1] = base1[tm].y;
                    b4[2] = base1[tm].z; b4[3] = base1[tm].w;
                    #pragma unroll
                    for (int r = 0; r < 4; ++r) {
                        int rl = wm * 64 + tm * 16 + quad4 + r;
                        float inv = __builtin_amdgcn_rcpf(fmaf(acc[tm][tn][r], -2.0f, b4[r] + c0));
                        ssum += (cl > rl) ? inv : 0.f;
                    }
                }
            }
        }
        #pragma unroll
        for (int m = 32; m >= 1; m >>= 1) ssum += __shfl_xor(ssum, m, 64);
        if (lane == 0) red[w] = ssum;
        __syncthreads();
        if (t == 0) partA[z] = red[0] + red[1] + red[2] + red[3];
    } else {
        // -------- sampled-pair path: fp8 rows (1 line/row), direct diff --------
        int pb = zb >> 1;                // [0, 2080)
        int pw = pb * 4 + w;             // [0, 8320)
        int g = lane >> 3;               // pair slot (0..7)
        int s = lane & 7;                // 8B chunk slot within the 64B row
        const uint2* W8v = (const uint2*)W8;   // row = 8 uint2
        float a1 = 0.f, a3 = 0.f;

        #pragma unroll 2
        for (int p0 = pw * 16; p0 < nb; p0 += NPW * 16) {
            int  pA = p0 + g,        pB = p0 + 8 + g;
            bool okA = pA < nb,      okB = pB < nb;
            int  cA = okA ? pA : 0,  cB = okB ? pB : 0;
            int   iA = ii[cA], jA = jj[cA];
            int   iB = ii[cB], jB = jj[cB];
            float pvA = pij[cA], pvB = pij[cB];
            uint2 xa = W8v[iA * 8 + s], ya = W8v[jA * 8 + s];
            uint2 xb = W8v[iB * 8 + s], yb = W8v[jB * 8 + s];

            float vA, vB;
            {
                f32x2 d0 = cvt2<false>(xa.x) - cvt2<false>(ya.x);
                f32x2 d1 = cvt2<true >(xa.x) - cvt2<true >(ya.x);
                f32x2 d2 = cvt2<false>(xa.y) - cvt2<false>(ya.y);
                f32x2 d3 = cvt2<true >(xa.y) - cvt2<true >(ya.y);
                f32x2 acc2 = d0 * d0;
                acc2 += d1 * d1; acc2 += d2 * d2; acc2 += d3 * d3;
                vA = acc2.x + acc2.y;
            }
            {
                f32x2 d0 = cvt2<false>(xb.x) - cvt2<false>(yb.x);
                f32x2 d1 = cvt2<true >(xb.x) - cvt2<true >(yb.x);
                f32x2 d2 = cvt2<false>(xb.y) - cvt2<false>(yb.y);
                f32x2 d3 = cvt2<true >(xb.y) - cvt2<true >(yb.y);
                f32x2 acc2 = d0 * d0;
                acc2 += d1 * d1; acc2 += d2 * d2; acc2 += d3 * d3;
                vB = acc2.x + acc2.y;
            }
            #pragma unroll
            for (int m = 1; m <= 4; m <<= 1) {
                vA += __shfl_xor(vA, m, 64);
                vB += __shfl_xor(vB, m, 64);
            }
            float tA = pvA * __logf(pvA * ((float)NDIM + vA));
            float tB = pvB * __logf(pvB * ((float)NDIM + vB));
            a1 += okA ? tA : 0.f;  a3 += okA ? pvA : 0.f;
            a1 += okB ? tB : 0.f;  a3 += okB ? pvB : 0.f;
        }
        #pragma unroll
        for (int m = 32; m >= 1; m >>= 1) {
            a1 += __shfl_xor(a1, m, 64);
            a3 += __shfl_xor(a3, m, 64);
        }
        if (lane == 0) { red[w] = a1 * 0.125f; red[4 + w] = a3 * 0.125f; }  // 8x lane redundancy
        __syncthreads();
        if (t == 0) {
            a1p[pb] = red[0] + red[1] + red[2] + red[3];
            a3p[pb] = red[4] + red[5] + red[6] + red[7];
        }
    }
}

__global__ __launch_bounds__(256) void final_kernel(const float* __restrict__ partA,
                                                    const float* __restrict__ a1p,
                                                    const float* __restrict__ a3p,
                                                    float* __restrict__ out) {
    __shared__ double r1[256], r2[256], r3[256];
    int t = threadIdx.x;
    double dpart = 0.0, d1 = 0.0, d3 = 0.0;
    for (int k = t; k < NBLK; k += 256) dpart += (double)partA[k];
    for (int k = t; k < NPAIRB; k += 256) { d1 += (double)a1p[k]; d3 += (double)a3p[k]; }
    r1[t] = dpart; r2[t] = d1; r3[t] = d3;
    __syncthreads();
    for (int s = 128; s >= 1; s >>= 1) {
        if (t < s) { r1[t] += r1[t + s]; r2[t] += r2[t + s]; r3[t] += r3[t + s]; }
        __syncthreads();
    }
    if (t == 0) {
        double part = 2.0 * r1[0];                 // sum over a<b, doubled; diagonal cancels -n
        out[0] = (float)(r2[0] + r3[0] * log(part));
    }
}

extern "C" void kernel_launch(void* const* d_in, const int* in_sizes, int n_in,
                              void* d_out, int out_size, void* d_ws, size_t ws_size,
                              hipStream_t stream) {
    const float* pij = (const float*)d_in[0];
    const int*   ii  = (const int*)d_in[1];
    const int*   jj  = (const int*)d_in[2];
    const float* W   = (const float*)d_in[3];
    float* out = (float*)d_out;
    float* ws  = (float*)d_ws;

    unsigned* W16   = (unsigned*)ws + WS_W16;
    unsigned* W8    = (unsigned*)ws + WS_W8;
    float*    sqv   = ws + WS_SQ;
    float*    partA = ws + WS_PARTA;
    float*    a1p   = ws + WS_A1P;
    float*    a3p   = ws + WS_A3P;

    int nb = in_sizes[0];   // number of sampled pairs (B)

    prep_kernel<<<NPOINTS / 4, 256, 0, stream>>>(W, sqv, W16, W8);
    fused_kernel<<<GRID, 256, 0, stream>>>(W16, W8, sqv, pij, ii, jj, nb, partA, a1p, a3p);
    final_kernel<<<1, 256, 0, stream>>>(partA, a1p, a3p, out);
}

// Round 8
// 102.256 us; speedup vs baseline: 1.1544x; 1.1544x over previous
//
#include <hip/hip_runtime.h>
#include <math.h>

// Problem constants (fixed by the reference file)
#define NPOINTS   8192
#define NDIM      64
#define TILE      128          // pairwise output tile per block
#define NT2       64           // NPOINTS / TILE
#define NBLK      2080         // NT2*(NT2+1)/2 triangle tiles

// ws dword/float layout:
//  [0, 262144)        W16   : W as bf16, packed 2/dword (8192 rows x 32 dwords)
//  [262144, 393216)   W8    : W as fp8 e4m3, packed 4/dword (8192 rows x 16 dwords)
//  [393216, 401408)   sq    : row squared norms (fp32 exact)
//  [401408, 403488)   partA : per-tile partials of sum 1/(1+d2) over a<b  (2080)
//  [403488, 407584)   a1p   : per-pair-block partials of sum pij*log(pij*(64+d2))
//  [407584, 411680)   a3p   : per-pair-block partials of sum pij
#define WS_W16   0
#define WS_W8    262144
#define WS_SQ    393216
#define WS_PARTA 401408
#define WS_A1P   403488
#define WS_A3P   407584

typedef __attribute__((ext_vector_type(8))) short bf16x8;   // 8 bf16 = 4 VGPRs (MFMA A/B frag)
typedef __attribute__((ext_vector_type(4))) float f32x4;    // MFMA C/D frag
typedef __attribute__((ext_vector_type(2))) float f32x2;

__device__ inline unsigned short f2bf(float f) {            // fp32 -> bf16 RNE
    unsigned u = __float_as_uint(f);
    u += 0x7FFFu + ((u >> 16) & 1u);
    return (unsigned short)(u >> 16);
}
template <bool HI>
__device__ inline f32x2 cvt2(unsigned dw) {                 // 2 fp8 e4m3 -> 2 fp32 (HW cvt)
    return __builtin_amdgcn_cvt_pk_f32_fp8((int)dw, HI);    // word-sel must be constexpr
}
__device__ inline void sqacc(f32x2& s, unsigned a, unsigned b) {  // s += (deq(a)-deq(b))^2
    f32x2 dl = cvt2<false>(a) - cvt2<false>(b);
    f32x2 dh = cvt2<true >(a) - cvt2<true >(b);
    s += dl * dl;
    s += dh * dh;
}

// One wave per row: exact fp32 row norm + bf16 W16; first 64 threads of each
// block also pack the block's 4 rows into fp8 W8 (4 elems/dword, coalesced).
__global__ __launch_bounds__(256) void prep_kernel(const float* __restrict__ W,
                                                   float* __restrict__ sq,
                                                   unsigned* __restrict__ W16,
                                                   unsigned* __restrict__ W8) {
    int t    = threadIdx.x;
    int wid  = (blockIdx.x * 256 + t) >> 6;             // row
    int lane = t & 63;
    float v = W[wid * NDIM + lane];
    float s = v * v;
    #pragma unroll
    for (int m = 32; m >= 1; m >>= 1) s += __shfl_xor(s, m, 64);
    if (lane == 0) sq[wid] = s;
    unsigned bf   = f2bf(v);
    unsigned peer = (unsigned)__shfl_xor((int)bf, 1, 64);
    if ((lane & 1) == 0)                                 // even lane packs (elem l | elem l+1)
        W16[wid * 32 + (lane >> 1)] = (bf & 0xFFFFu) | (peer << 16);
    if (t < 64) {                                        // fp8 pack: 4 rows = 64 dwords/block
        float4 x = *(const float4*)(W + blockIdx.x * 256 + t * 4);
        int lo = __builtin_amdgcn_cvt_pk_fp8_f32(x.x, x.y, 0, false);
        int dw = __builtin_amdgcn_cvt_pk_fp8_f32(x.z, x.w, lo, true);
        W8[blockIdx.x * 64 + t] = (unsigned)dw;
    }
}

// One THREAD per sampled pair, one shot: coalesced index load -> 8 independent
// dwordx4 gathers (both full fp8 rows) -> in-register decode/diff -> 1 log.
// Exactly two dependent memory round-trips; no cross-lane ops until the final
// block reduction.
__global__ __launch_bounds__(256) void pair_kernel(const unsigned* __restrict__ W8,
                                                   const float* __restrict__ pij,
                                                   const int* __restrict__ ii,
                                                   const int* __restrict__ jj,
                                                   int nb,
                                                   float* __restrict__ a1p,
                                                   float* __restrict__ a3p) {
    int t = threadIdx.x;
    int p = blockIdx.x * 256 + t;
    float a1 = 0.f, a3 = 0.f;
    if (p < nb) {
        int   i  = ii[p];
        int   j  = jj[p];
        float pv = pij[p];
        const uint4* X = (const uint4*)(W8 + i * 16);
        const uint4* Y = (const uint4*)(W8 + j * 16);
        uint4 x0 = X[0], x1 = X[1], x2 = X[2], x3 = X[3];   // 8 independent 16B loads
        uint4 y0 = Y[0], y1 = Y[1], y2 = Y[2], y3 = Y[3];
        f32x2 s2 = {0.f, 0.f};
        sqacc(s2, x0.x, y0.x); sqacc(s2, x0.y, y0.y);
        sqacc(s2, x0.z, y0.z); sqacc(s2, x0.w, y0.w);
        sqacc(s2, x1.x, y1.x); sqacc(s2, x1.y, y1.y);
        sqacc(s2, x1.z, y1.z); sqacc(s2, x1.w, y1.w);
        sqacc(s2, x2.x, y2.x); sqacc(s2, x2.y, y2.y);
        sqacc(s2, x2.z, y2.z); sqacc(s2, x2.w, y2.w);
        sqacc(s2, x3.x, y3.x); sqacc(s2, x3.y, y3.y);
        sqacc(s2, x3.z, y3.z); sqacc(s2, x3.w, y3.w);
        float v = s2.x + s2.y;                              // ||xi-xj||^2
        a1 = pv * __logf(pv * ((float)NDIM + v));
        a3 = pv;
    }
    #pragma unroll
    for (int m = 32; m >= 1; m >>= 1) {
        a1 += __shfl_xor(a1, m, 64);
        a3 += __shfl_xor(a3, m, 64);
    }
    __shared__ float red[8];
    if ((t & 63) == 0) { red[t >> 6] = a1; red[4 + (t >> 6)] = a3; }
    __syncthreads();
    if (t == 0) {
        a1p[blockIdx.x] = red[0] + red[1] + red[2] + red[3];
        a3p[blockIdx.x] = red[4] + red[5] + red[6] + red[7];
    }
}

// 128x128 triangle tile of the Cauchy partition via bf16 MFMA; frags straight
// from global bf16. Frag layouts (HW-verified): A/B = X[idx=lane&15][k=(lane>>4)*8+j];
// C/D row=(lane>>4)*4+reg, col=lane&15.
__global__ __launch_bounds__(256) void pairwise_kernel(const unsigned* __restrict__ W16,
                                                       const float* __restrict__ sq,
                                                       float* __restrict__ partA) {
    int z = blockIdx.x;
    int t = threadIdx.x, w = t >> 6, lane = t & 63;
    int by = (int)((129.0 - sqrt(16641.0 - 8.0 * (double)z)) * 0.5);
    while (by * NT2 - by * (by - 1) / 2 > z) --by;
    while ((by + 1) * NT2 - (by + 1) * by / 2 <= z) ++by;
    int bx = by + (z - (by * NT2 - by * (by - 1) / 2));

    int wm = w >> 1, wn = w & 1, quad = lane >> 4, l15 = lane & 15;
    int a0 = by * TILE, b0 = bx * TILE;

    float4 base1[4];                 // 1 + sq[arow + tm*16 + 0..3]
    float  sqb[4];
    {
        int arow = a0 + wm * 64 + quad * 4;
        #pragma unroll
        for (int tm = 0; tm < 4; ++tm) {
            float4 v = *(const float4*)(sq + arow + tm * 16);
            base1[tm] = (float4){1.0f + v.x, 1.0f + v.y, 1.0f + v.z, 1.0f + v.w};
        }
        int bcol = b0 + wn * 64 + l15;
        #pragma unroll
        for (int tn = 0; tn < 4; ++tn) sqb[tn] = sq[bcol + tn * 16];
    }

    f32x4 acc[4][4];
    #pragma unroll
    for (int i = 0; i < 4; ++i)
        #pragma unroll
        for (int j = 0; j < 4; ++j) acc[i][j] = (f32x4){0.f, 0.f, 0.f, 0.f};

    const unsigned* Arow = W16 + (a0 + wm * 64 + l15) * 32;   // row pitch 32 dwords
    const unsigned* Brow = W16 + (b0 + wn * 64 + l15) * 32;
    #pragma unroll
    for (int h = 0; h < 2; ++h) {    // two K=32 halves; frag = 4 dwords, 16B-aligned
        bf16x8 af[4], bfr[4];
        #pragma unroll
        for (int tm = 0; tm < 4; ++tm)
            af[tm] = *(const bf16x8*)(Arow + tm * 16 * 32 + h * 16 + quad * 4);
        #pragma unroll
        for (int tn = 0; tn < 4; ++tn)
            bfr[tn] = *(const bf16x8*)(Brow + tn * 16 * 32 + h * 16 + quad * 4);
        #pragma unroll
        for (int tm = 0; tm < 4; ++tm)
            #pragma unroll
            for (int tn = 0; tn < 4; ++tn)
                acc[tm][tn] = __builtin_amdgcn_mfma_f32_16x16x32_bf16(af[tm], bfr[tn],
                                                                      acc[tm][tn], 0, 0, 0);
    }

    float ssum = 0.f;
    if (bx > by) {
        #pragma unroll
        for (int tn = 0; tn < 4; ++tn) {
            float c0 = sqb[tn];
            #pragma unroll
            for (int tm = 0; tm < 4; ++tm) {
                ssum += __builtin_amdgcn_rcpf(fmaf(acc[tm][tn][0], -2.0f, base1[tm].x + c0));
                ssum += __builtin_amdgcn_rcpf(fmaf(acc[tm][tn][1], -2.0f, base1[tm].y + c0));
                ssum += __builtin_amdgcn_rcpf(fmaf(acc[tm][tn][2], -2.0f, base1[tm].z + c0));
                ssum += __builtin_amdgcn_rcpf(fmaf(acc[tm][tn][3], -2.0f, base1[tm].w + c0));
            }
        }
    } else {                         // diagonal tile: strictly-upper only
        int quad4 = quad * 4;
        #pragma unroll
        for (int tn = 0; tn < 4; ++tn) {
            int cl = wn * 64 + tn * 16 + l15;
            float c0 = sqb[tn];
            float b4[4];
            #pragma unroll
            for (int tm = 0; tm < 4; ++tm) {
                b4[0] = base1[tm].x; b4[1] = base1[tm].y;
                b4[2] = base1[tm].z; b4[3] = base1[tm].w;
                #pragma unroll
                for (int r = 0; r < 4; ++r) {
                    int rl = wm * 64 + tm * 16 + quad4 + r;
                    float inv = __builtin_amdgcn_rcpf(fmaf(acc[tm][tn][r], -2.0f, b4[r] + c0));
                    ssum += (cl > rl) ? inv : 0.f;
                }
            }
        }
    }
    #pragma unroll
    for (int m = 32; m >= 1; m >>= 1) ssum += __shfl_xor(ssum, m, 64);
    __shared__ float wsum[4];
    if (lane == 0) wsum[w] = ssum;
    __syncthreads();
    if (t == 0) partA[z] = wsum[0] + wsum[1] + wsum[2] + wsum[3];
}

__global__ __launch_bounds__(256) void final_kernel(const float* __restrict__ partA,
                                                    const float* __restrict__ a1p,
                                                    const float* __restrict__ a3p,
                                                    int npb,
                                                    float* __restrict__ out) {
    __shared__ double r1[256], r2[256], r3[256];
    int t = threadIdx.x;
    double dpart = 0.0, d1 = 0.0, d3 = 0.0;
    for (int k = t; k < NBLK; k += 256) dpart += (double)partA[k];
    for (int k = t; k < npb; k += 256) { d1 += (double)a1p[k]; d3 += (double)a3p[k]; }
    r1[t] = dpart; r2[t] = d1; r3[t] = d3;
    __syncthreads();
    for (int s = 128; s >= 1; s >>= 1) {
        if (t < s) { r1[t] += r1[t + s]; r2[t] += r2[t + s]; r3[t] += r3[t + s]; }
        __syncthreads();
    }
    if (t == 0) {
        double part = 2.0 * r1[0];                 // sum over a<b, doubled; diagonal cancels -n
        out[0] = (float)(r2[0] + r3[0] * log(part));
    }
}

extern "C" void kernel_launch(void* const* d_in, const int* in_sizes, int n_in,
                              void* d_out, int out_size, void* d_ws, size_t ws_size,
                              hipStream_t stream) {
    const float* pij = (const float*)d_in[0];
    const int*   ii  = (const int*)d_in[1];
    const int*   jj  = (const int*)d_in[2];
    const float* W   = (const float*)d_in[3];
    float* out = (float*)d_out;
    float* ws  = (float*)d_ws;

    unsigned* W16   = (unsigned*)ws + WS_W16;
    unsigned* W8    = (unsigned*)ws + WS_W8;
    float*    sqv   = ws + WS_SQ;
    float*    partA = ws + WS_PARTA;
    float*    a1p   = ws + WS_A1P;
    float*    a3p   = ws + WS_A3P;

    int nb  = in_sizes[0];            // number of sampled pairs (B)
    int npb = (nb + 255) / 256;       // pair-kernel blocks (2048 for B=524288)

    prep_kernel<<<NPOINTS / 4, 256, 0, stream>>>(W, sqv, W16, W8);
    pair_kernel<<<npb, 256, 0, stream>>>(W8, pij, ii, jj, nb, a1p, a3p);
    pairwise_kernel<<<NBLK, 256, 0, stream>>>(W16, sqv, partA);
    final_kernel<<<1, 256, 0, stream>>>(partA, a1p, a3p, npb, out);
}

// Round 9
// 90.925 us; speedup vs baseline: 1.2983x; 1.1246x over previous
//
#include <hip/hip_runtime.h>
#include <math.h>

// Problem constants (fixed by the reference file)
#define NPOINTS   8192
#define NDIM      64
#define TILE      128          // pairwise output tile per block
#define NT2       64           // NPOINTS / TILE
#define NBLK      2080         // NT2*(NT2+1)/2 triangle tiles
#define NGRP      512          // NPOINTS / 16 row-groups (prep blocks)

// ws dword/float layout:
//  [0, 262144)        W16f  : W as bf16 in MFMA-fragment order:
//                             chunk c = (rowgroup g)*2 + h  (g=row/16, h=K-half)
//                             dword addr = c*256 + lane*4 + d ; lane=quad*16+l15
//                             holds row g*16+l15, bf16 elems h*32+quad*8 .. +8
//  [262144, 393216)   W8    : W as fp8 e4m3, packed 4/dword (8192 rows x 16 dwords)
//  [393216, 401408)   sq    : row squared norms (fp32 exact)
//  [401408, 403488)   partA : per-tile partials of sum 1/(1+d2) over a<b  (2080)
//  [403488, 407584)   a1p   : per-pair-block partials of sum pij*log(pij*(64+d2))
//  [407584, 411680)   a3p   : per-pair-block partials of sum pij
#define WS_W16   0
#define WS_W8    262144
#define WS_SQ    393216
#define WS_PARTA 401408
#define WS_A1P   403488
#define WS_A3P   407584

typedef __attribute__((ext_vector_type(8))) short bf16x8;   // 8 bf16 = 4 VGPRs (MFMA A/B frag)
typedef __attribute__((ext_vector_type(4))) float f32x4;    // MFMA C/D frag
typedef __attribute__((ext_vector_type(2))) float f32x2;

__device__ inline unsigned f2bf_pk(float lo, float hi) {    // pack 2 fp32 -> 2 bf16 (RNE)
    unsigned ul = __float_as_uint(lo), uh = __float_as_uint(hi);
    ul += 0x7FFFu + ((ul >> 16) & 1u);
    uh += 0x7FFFu + ((uh >> 16) & 1u);
    return (ul >> 16) | (uh & 0xFFFF0000u);
}
template <bool HI>
__device__ inline f32x2 cvt2(unsigned dw) {                 // 2 fp8 e4m3 -> 2 fp32 (HW cvt)
    return __builtin_amdgcn_cvt_pk_f32_fp8((int)dw, HI);    // word-sel must be constexpr
}
__device__ inline void sqacc(f32x2& s, unsigned a, unsigned b) {  // s += (deq(a)-deq(b))^2
    f32x2 dl = cvt2<false>(a) - cvt2<false>(b);
    f32x2 dh = cvt2<true >(a) - cvt2<true >(b);
    s += dl * dl;
    s += dh * dh;
}

// One block per 16-row group g: emits (1) W16f fragment-order bf16, (2) exact
// fp32 row norms, (3) fp8 rows for the pair path. All loads/stores coalesced.
__global__ __launch_bounds__(256) void prep_kernel(const float* __restrict__ W,
                                                   float* __restrict__ sq,
                                                   unsigned* __restrict__ W16f,
                                                   unsigned* __restrict__ W8) {
    int g = blockIdx.x;
    int t = threadIdx.x;

    // ---- (1) fragment-order bf16: thread t -> (h, L, dpair), 4 floats -> uint2
    {
        int h = t >> 7, L = (t >> 1) & 63, dp = t & 1;
        int row = g * 16 + (L & 15), quad = L >> 4;
        float4 v = *(const float4*)(W + row * NDIM + h * 32 + quad * 8 + dp * 4);
        uint2 o;
        o.x = f2bf_pk(v.x, v.y);
        o.y = f2bf_pk(v.z, v.w);
        *(uint2*)(W16f + ((g * 2 + h) * 256 + L * 4 + dp * 2)) = o;
    }
    // ---- (2) exact row norms: thread t -> row r=t>>4, slice s=t&15 (4 elems)
    {
        int r = t >> 4, s = t & 15;
        float4 v = *(const float4*)(W + (g * 16 + r) * NDIM + s * 4);
        float p = v.x * v.x + v.y * v.y + v.z * v.z + v.w * v.w;
        p += __shfl_xor(p, 1, 64);
        p += __shfl_xor(p, 2, 64);
        p += __shfl_xor(p, 4, 64);
        p += __shfl_xor(p, 8, 64);
        if (s == 0) sq[g * 16 + r] = p;
    }
    // ---- (3) fp8 rows: thread t -> row t>>4, dword t&15
    {
        int r = g * 16 + (t >> 4), d = t & 15;
        float4 x = *(const float4*)(W + r * NDIM + d * 4);
        int lo = __builtin_amdgcn_cvt_pk_fp8_f32(x.x, x.y, 0, false);
        int dw = __builtin_amdgcn_cvt_pk_fp8_f32(x.z, x.w, lo, true);
        W8[r * 16 + d] = (unsigned)dw;
    }
}

// One THREAD per sampled pair, one shot: coalesced index load -> 8 independent
// dwordx4 gathers (both full fp8 rows) -> in-register decode/diff -> 1 log.
__global__ __launch_bounds__(256) void pair_kernel(const unsigned* __restrict__ W8,
                                                   const float* __restrict__ pij,
                                                   const int* __restrict__ ii,
                                                   const int* __restrict__ jj,
                                                   int nb,
                                                   float* __restrict__ a1p,
                                                   float* __restrict__ a3p) {
    int t = threadIdx.x;
    int p = blockIdx.x * 256 + t;
    float a1 = 0.f, a3 = 0.f;
    if (p < nb) {
        int   i  = ii[p];
        int   j  = jj[p];
        float pv = pij[p];
        const uint4* X = (const uint4*)(W8 + i * 16);
        const uint4* Y = (const uint4*)(W8 + j * 16);
        uint4 x0 = X[0], x1 = X[1], x2 = X[2], x3 = X[3];   // 8 independent 16B loads
        uint4 y0 = Y[0], y1 = Y[1], y2 = Y[2], y3 = Y[3];
        f32x2 s2 = {0.f, 0.f};
        sqacc(s2, x0.x, y0.x); sqacc(s2, x0.y, y0.y);
        sqacc(s2, x0.z, y0.z); sqacc(s2, x0.w, y0.w);
        sqacc(s2, x1.x, y1.x); sqacc(s2, x1.y, y1.y);
        sqacc(s2, x1.z, y1.z); sqacc(s2, x1.w, y1.w);
        sqacc(s2, x2.x, y2.x); sqacc(s2, x2.y, y2.y);
        sqacc(s2, x2.z, y2.z); sqacc(s2, x2.w, y2.w);
        sqacc(s2, x3.x, y3.x); sqacc(s2, x3.y, y3.y);
        sqacc(s2, x3.z, y3.z); sqacc(s2, x3.w, y3.w);
        float v = s2.x + s2.y;                              // ||xi-xj||^2
        a1 = pv * __logf(pv * ((float)NDIM + v));
        a3 = pv;
    }
    #pragma unroll
    for (int m = 32; m >= 1; m >>= 1) {
        a1 += __shfl_xor(a1, m, 64);
        a3 += __shfl_xor(a3, m, 64);
    }
    __shared__ float red[8];
    if ((t & 63) == 0) { red[t >> 6] = a1; red[4 + (t >> 6)] = a3; }
    __syncthreads();
    if (t == 0) {
        a1p[blockIdx.x] = red[0] + red[1] + red[2] + red[3];
        a3p[blockIdx.x] = red[4] + red[5] + red[6] + red[7];
    }
}

// 128x128 triangle tile of the Cauchy partition via bf16 MFMA. Fragments load
// from the pre-swizzled W16f: one dwordx4 per lane, 64 lanes CONTIGUOUS (1 KB
// per instruction, 16 sequential cache lines) — no scattered line requests.
// Frag layouts (HW-verified): A/B = X[idx=lane&15][k=(lane>>4)*8+j];
// C/D row=(lane>>4)*4+reg, col=lane&15.
__global__ __launch_bounds__(256) void pairwise_kernel(const unsigned* __restrict__ W16f,
                                                       const float* __restrict__ sq,
                                                       float* __restrict__ partA) {
    int z = blockIdx.x;
    int t = threadIdx.x, w = t >> 6, lane = t & 63;
    int by = (int)((129.0f - sqrtf((float)(16641 - 8 * z))) * 0.5f);
    while (by * NT2 - by * (by - 1) / 2 > z) --by;
    while ((by + 1) * NT2 - (by + 1) * by / 2 <= z) ++by;
    int bx = by + (z - (by * NT2 - by * (by - 1) / 2));

    int wm = w >> 1, wn = w & 1, quad = lane >> 4, l15 = lane & 15;
    int a0 = by * TILE, b0 = bx * TILE;

    float4 base1[4];                 // 1 + sq[arow + tm*16 + 0..3]
    float  sqb[4];
    {
        int arow = a0 + wm * 64 + quad * 4;
        #pragma unroll
        for (int tm = 0; tm < 4; ++tm) {
            float4 v = *(const float4*)(sq + arow + tm * 16);
            base1[tm] = (float4){1.0f + v.x, 1.0f + v.y, 1.0f + v.z, 1.0f + v.w};
        }
        int bcol = b0 + wn * 64 + l15;
        #pragma unroll
        for (int tn = 0; tn < 4; ++tn) sqb[tn] = sq[bcol + tn * 16];
    }

    f32x4 acc[4][4];
    #pragma unroll
    for (int i = 0; i < 4; ++i)
        #pragma unroll
        for (int j = 0; j < 4; ++j) acc[i][j] = (f32x4){0.f, 0.f, 0.f, 0.f};

    int gA = (a0 >> 4) + wm * 4;     // A row-groups gA+tm; B row-groups gB+tn
    int gB = (b0 >> 4) + wn * 4;
    #pragma unroll
    for (int h = 0; h < 2; ++h) {    // two K=32 halves; 1 KB contiguous per frag
        bf16x8 af[4], bfr[4];
        #pragma unroll
        for (int tm = 0; tm < 4; ++tm)
            af[tm] = *(const bf16x8*)(W16f + (((gA + tm) * 2 + h) * 256 + lane * 4));
        #pragma unroll
        for (int tn = 0; tn < 4; ++tn)
            bfr[tn] = *(const bf16x8*)(W16f + (((gB + tn) * 2 + h) * 256 + lane * 4));
        #pragma unroll
        for (int tm = 0; tm < 4; ++tm)
            #pragma unroll
            for (int tn = 0; tn < 4; ++tn)
                acc[tm][tn] = __builtin_amdgcn_mfma_f32_16x16x32_bf16(af[tm], bfr[tn],
                                                                      acc[tm][tn], 0, 0, 0);
    }

    float ssum = 0.f;
    if (bx > by) {
        #pragma unroll
        for (int tn = 0; tn < 4; ++tn) {
            float c0 = sqb[tn];
            #pragma unroll
            for (int tm = 0; tm < 4; ++tm) {
                ssum += __builtin_amdgcn_rcpf(fmaf(acc[tm][tn][0], -2.0f, base1[tm].x + c0));
                ssum += __builtin_amdgcn_rcpf(fmaf(acc[tm][tn][1], -2.0f, base1[tm].y + c0));
                ssum += __builtin_amdgcn_rcpf(fmaf(acc[tm][tn][2], -2.0f, base1[tm].z + c0));
                ssum += __builtin_amdgcn_rcpf(fmaf(acc[tm][tn][3], -2.0f, base1[tm].w + c0));
            }
        }
    } else {                         // diagonal tile: strictly-upper only
        int quad4 = quad * 4;
        #pragma unroll
        for (int tn = 0; tn < 4; ++tn) {
            int cl = wn * 64 + tn * 16 + l15;
            float c0 = sqb[tn];
            float b4[4];
            #pragma unroll
            for (int tm = 0; tm < 4; ++tm) {
                b4[0] = base1[tm].x; b4[1] = base1[tm].y;
                b4[2] = base1[tm].z; b4[3] = base1[tm].w;
                #pragma unroll
                for (int r = 0; r < 4; ++r) {
                    int rl = wm * 64 + tm * 16 + quad4 + r;
                    float inv = __builtin_amdgcn_rcpf(fmaf(acc[tm][tn][r], -2.0f, b4[r] + c0));
                    ssum += (cl > rl) ? inv : 0.f;
                }
            }
        }
    }
    #pragma unroll
    for (int m = 32; m >= 1; m >>= 1) ssum += __shfl_xor(ssum, m, 64);
    __shared__ float wsum[4];
    if (lane == 0) wsum[w] = ssum;
    __syncthreads();
    if (t == 0) partA[z] = wsum[0] + wsum[1] + wsum[2] + wsum[3];
}

__global__ __launch_bounds__(256) void final_kernel(const float* __restrict__ partA,
                                                    const float* __restrict__ a1p,
                                                    const float* __restrict__ a3p,
                                                    int npb,
                                                    float* __restrict__ out) {
    __shared__ double r1[256], r2[256], r3[256];
    int t = threadIdx.x;
    double dpart = 0.0, d1 = 0.0, d3 = 0.0;
    for (int k = t; k < NBLK; k += 256) dpart += (double)partA[k];
    for (int k = t; k < npb; k += 256) { d1 += (double)a1p[k]; d3 += (double)a3p[k]; }
    r1[t] = dpart; r2[t] = d1; r3[t] = d3;
    __syncthreads();
    for (int s = 128; s >= 1; s >>= 1) {
        if (t < s) { r1[t] += r1[t + s]; r2[t] += r2[t + s]; r3[t] += r3[t + s]; }
        __syncthreads();
    }
    if (t == 0) {
        double part = 2.0 * r1[0];                 // sum over a<b, doubled; diagonal cancels -n
        out[0] = (float)(r2[0] + r3[0] * log(part));
    }
}

extern "C" void kernel_launch(void* const* d_in, const int* in_sizes, int n_in,
                              void* d_out, int out_size, void* d_ws, size_t ws_size,
                              hipStream_t stream) {
    const float* pij = (const float*)d_in[0];
    const int*   ii  = (const int*)d_in[1];
    const int*   jj  = (const int*)d_in[2];
    const float* W   = (const float*)d_in[3];
    float* out = (float*)d_out;
    float* ws  = (float*)d_ws;

    unsigned* W16f  = (unsigned*)ws + WS_W16;
    unsigned* W8    = (unsigned*)ws + WS_W8;
    float*    sqv   = ws + WS_SQ;
    float*    partA = ws + WS_PARTA;
    float*    a1p   = ws + WS_A1P;
    float*    a3p   = ws + WS_A3P;

    int nb  = in_sizes[0];            // number of sampled pairs (B)
    int npb = (nb + 255) / 256;       // pair-kernel blocks (2048 for B=524288)

    prep_kernel<<<NGRP, 256, 0, stream>>>(W, sqv, W16f, W8);
    pair_kernel<<<npb, 256, 0, stream>>>(W8, pij, ii, jj, nb, a1p, a3p);
    pairwise_kernel<<<NBLK, 256, 0, stream>>>(W16f, sqv, partA);
    final_kernel<<<1, 256, 0, stream>>>(partA, a1p, a3p, npb, out);
}